// Round 4
// baseline (684.087 us; speedup 1.0000x reference)
//
#include <hip/hip_runtime.h>

// ---------------------------------------------------------------------------
// QuantizedPermutationNoiseLinear  (B=4, S=2048, IN=4096, OUT=1024, ROUNDS=12)
//
// res = QDQ(T(x+nx)) @ QDQ(Tw(w+wn)).T + bias - x@wn.T - nx@(w+wn).T
//
// R7 changes vs R6:
//  - transform: 4 rows/block (was 2), 128 KB dynamic LDS, float4-packed,
//    XOR slot-swizzle for conflict-free pack/unpack. Halves per-block table
//    re-read traffic (was 2.2 GB aggregate L2).
//  - quant: 4 rows/block.
//  - gemm: all 24 ds_reads front-loaded in j0 (counted lgkmcnt overlaps LDS
//    drain with j0/j1 MFMA); j3 vmcnt moved after its MFMA cluster. Barrier/
//    vmcnt ledger unchanged (R6: bank conflicts == 0, keep).
// ---------------------------------------------------------------------------

#define IN_F   4096
#define OUT_F  1024
#define MROWS  8192          // B*S
#define KTOT   12288
#define KHALF  6144
#define NPASS  6             // merged rounds (12 -> 6)
#define NTIL   96            // K-tiles per split (6144/64)

typedef _Float16 f16;
typedef _Float16 f16x8 __attribute__((ext_vector_type(8)));
typedef _Float16 f16x4 __attribute__((ext_vector_type(4)));
typedef float    f32x4 __attribute__((ext_vector_type(4)));

// ---- workspace layout (bytes) --- total ~379 MB ---------------------------
#define OFF_XT  (0ull)                                   // 8192*4096*4 = 128 MB
#define OFF_WT  (OFF_XT + (size_t)MROWS * IN_F * 4)      // 1024*4096*4 = 16 MB
#define OFF_A   (OFF_WT + (size_t)OUT_F * IN_F * 4)      // 8192*12288*2 = 192 MB
#define OFF_B   (OFF_A + (size_t)MROWS * KTOT * 2)       // 1024*12288*2 = 24 MB
#define OFF_MM  (OFF_B + (size_t)OUT_F * KTOT * 2)       // 4 u32 + 4 f32
#define OFF_TIX (OFF_MM + 256)                           // 6*2048*8  = 96 KB
#define OFF_TCX (OFF_TIX + (size_t)NPASS * 2048 * 8)     // 6*2048*32 = 384 KB
#define OFF_TIW (OFF_TCX + (size_t)NPASS * 2048 * 32)
#define OFF_TCW (OFF_TIW + (size_t)NPASS * 2048 * 8)

// LDS slot swizzle (transform): spreads stride-4 float4 writes across all
// eight 16B positions per 128B period -> 8 lanes/position = HW minimum.
#define SW(s) ((s) ^ (((s) >> 3) & 7))

// ---- sortable-uint encoding for float atomic min/max ----------------------
__device__ __forceinline__ unsigned enc_f(float f) {
  unsigned u = __float_as_uint(f);
  return (u & 0x80000000u) ? ~u : (u | 0x80000000u);
}
__device__ __forceinline__ float dec_f(unsigned u) {
  unsigned b = (u & 0x80000000u) ? (u & 0x7fffffffu) : ~u;
  return __uint_as_float(b);
}

// y = cA.x*x0 + cA.y*x1 + cA.z*x2 + cA.w*x3   (component-wise over 4 rows)
__device__ __forceinline__ float4 f4comb(float4 c, float4 x0, float4 x1,
                                         float4 x2, float4 x3) {
  return make_float4(c.x * x0.x + c.y * x1.x + c.z * x2.x + c.w * x3.x,
                     c.x * x0.y + c.y * x1.y + c.z * x2.y + c.w * x3.y,
                     c.x * x0.z + c.y * x1.z + c.z * x2.z + c.w * x3.z,
                     c.x * x0.w + c.y * x1.w + c.z * x2.w + c.w * x3.w);
}

// ---------------------------------------------------------------------------
// Build merged-round tables (pass p composes rounds 2p, 2p+1). Also inits mm.
// ---------------------------------------------------------------------------
__global__ void build_tables_kernel(const int* __restrict__ perms,
                                    const float* __restrict__ mats,
                                    uint2* __restrict__ tIx, float4* __restrict__ tCx,
                                    uint2* __restrict__ tIw, float4* __restrict__ tCw,
                                    unsigned* __restrict__ mm) {
  if (blockIdx.x == 0 && threadIdx.x == 0) {
    mm[0] = 0xFFFFFFFFu; mm[1] = 0u; mm[2] = 0xFFFFFFFFu; mm[3] = 0u;
  }
  int p = blockIdx.x;  // 0..5
  int r0 = 2 * p, r1 = 2 * p + 1;
  for (int g = threadIdx.x; g < 2048; g += blockDim.x) {
    int q0 = perms[r1 * IN_F + 2 * g], q1 = perms[r1 * IN_F + 2 * g + 1];
    int a0 = q0 >> 1, e0 = q0 & 1, a1 = q1 >> 1, e1 = q1 & 1;
    unsigned i0 = perms[r0 * IN_F + 2 * a0], i1 = perms[r0 * IN_F + 2 * a0 + 1];
    unsigned i2 = perms[r0 * IN_F + 2 * a1], i3 = perms[r0 * IN_F + 2 * a1 + 1];
    uint2 idx = make_uint2(i0 | (i1 << 16), i2 | (i3 << 16));
    const float* Ma = mats + ((size_t)r0 * 2048 + a0) * 4;  // [a,b,c,d]
    const float* Mb = mats + ((size_t)r0 * 2048 + a1) * 4;
    const float* M1 = mats + ((size_t)r1 * 2048 + g) * 4;
    int o = p * 2048 + g;
    { // forward
      float c00 = Ma[e0 * 2], c01 = Ma[e0 * 2 + 1];
      float c10 = Mb[e1 * 2], c11 = Mb[e1 * 2 + 1];
      float m00 = M1[0], m01 = M1[1], m10 = M1[2], m11 = M1[3];
      tIx[o] = idx;
      tCx[2 * o]     = make_float4(m00 * c00, m00 * c01, m01 * c10, m01 * c11);
      tCx[2 * o + 1] = make_float4(m10 * c00, m10 * c01, m11 * c10, m11 * c11);
    }
    { // inverse-transpose (weight): N = [[d,-c],[-b,a]]/det
      float rda = 1.0f / (Ma[0] * Ma[3] - Ma[1] * Ma[2]);
      float rdb = 1.0f / (Mb[0] * Mb[3] - Mb[1] * Mb[2]);
      float rd1 = 1.0f / (M1[0] * M1[3] - M1[1] * M1[2]);
      float c00 = (e0 == 0 ? Ma[3] : -Ma[1]) * rda;
      float c01 = (e0 == 0 ? -Ma[2] : Ma[0]) * rda;
      float c10 = (e1 == 0 ? Mb[3] : -Mb[1]) * rdb;
      float c11 = (e1 == 0 ? -Mb[2] : Mb[0]) * rdb;
      float m00 = M1[3] * rd1, m01 = -M1[2] * rd1;
      float m10 = -M1[1] * rd1, m11 = M1[0] * rd1;
      tIw[o] = idx;
      tCw[2 * o]     = make_float4(m00 * c00, m00 * c01, m01 * c10, m01 * c11);
      tCw[2 * o + 1] = make_float4(m10 * c00, m10 * c01, m11 * c10, m11 * c11);
    }
  }
}

// ---------------------------------------------------------------------------
// Transform: 1024 threads, 4 rows/block (float4-packed), 6 merged LDS passes.
// 128 KB dynamic LDS = 2 planes x 4096 float4, XOR slot swizzle.
// ---------------------------------------------------------------------------
__global__ __launch_bounds__(1024) void transform_kernel(
    const float* __restrict__ x, const float* __restrict__ nx,
    const float* __restrict__ w, const float* __restrict__ wn,
    const uint2* __restrict__ tIx, const float4* __restrict__ tCx,
    const uint2* __restrict__ tIw, const float4* __restrict__ tCw,
    float* __restrict__ xt, float* __restrict__ wt,
    f16* __restrict__ Aall, f16* __restrict__ Ball,
    unsigned* __restrict__ mm) {
  extern __shared__ float4 buf[];   // [2][4096]
  const int t = threadIdx.x;
  const bool isW = blockIdx.x >= (MROWS / 4);
  const float *in0, *in1; const uint2* tI; const float4* tC;
  float* tout; f16* fout; int mmidx; size_t m0;
  if (!isW) {
    m0 = (size_t)blockIdx.x * 4;
    in0 = x; in1 = nx; tI = tIx; tC = tCx; tout = xt; fout = Aall; mmidx = 0;
  } else {
    m0 = (size_t)(blockIdx.x - MROWS / 4) * 4;
    in0 = w; in1 = wn; tI = tIw; tC = tCw; tout = wt; fout = Ball; mmidx = 2;
  }

  { // load 4 rows, pack columns into float4 slots, emit f16 side-outputs
    float4 a0 = ((const float4*)(in0 + (m0 + 0) * IN_F))[t];
    float4 a1 = ((const float4*)(in0 + (m0 + 1) * IN_F))[t];
    float4 a2 = ((const float4*)(in0 + (m0 + 2) * IN_F))[t];
    float4 a3 = ((const float4*)(in0 + (m0 + 3) * IN_F))[t];
    float4 b0 = ((const float4*)(in1 + (m0 + 0) * IN_F))[t];
    float4 b1 = ((const float4*)(in1 + (m0 + 1) * IN_F))[t];
    float4 b2 = ((const float4*)(in1 + (m0 + 2) * IN_F))[t];
    float4 b3 = ((const float4*)(in1 + (m0 + 3) * IN_F))[t];
    float4 s0 = make_float4(a0.x + b0.x, a0.y + b0.y, a0.z + b0.z, a0.w + b0.w);
    float4 s1 = make_float4(a1.x + b1.x, a1.y + b1.y, a1.z + b1.z, a1.w + b1.w);
    float4 s2 = make_float4(a2.x + b2.x, a2.y + b2.y, a2.z + b2.z, a2.w + b2.w);
    float4 s3 = make_float4(a3.x + b3.x, a3.y + b3.y, a3.z + b3.z, a3.w + b3.w);
    int c = t * 4;
    buf[SW(c + 0)] = make_float4(s0.x, s1.x, s2.x, s3.x);
    buf[SW(c + 1)] = make_float4(s0.y, s1.y, s2.y, s3.y);
    buf[SW(c + 2)] = make_float4(s0.z, s1.z, s2.z, s3.z);
    buf[SW(c + 3)] = make_float4(s0.w, s1.w, s2.w, s3.w);
#pragma unroll
    for (int r = 0; r < 4; r++) {
      float4 av = r == 0 ? a0 : r == 1 ? a1 : r == 2 ? a2 : a3;
      float4 bv = r == 0 ? b0 : r == 1 ? b1 : r == 2 ? b2 : b3;
      float4 sv = r == 0 ? s0 : r == 1 ? s1 : r == 2 ? s2 : s3;
      f16* fr = fout + (m0 + r) * KTOT;
      f16x4 p, q;
      if (isW) {
        p.x=(f16)bv.x; p.y=(f16)bv.y; p.z=(f16)bv.z; p.w=(f16)bv.w;   // wn
        q.x=(f16)sv.x; q.y=(f16)sv.y; q.z=(f16)sv.z; q.w=(f16)sv.w;   // w+wn
      } else {
        p.x=(f16)(-av.x); p.y=(f16)(-av.y); p.z=(f16)(-av.z); p.w=(f16)(-av.w); // -x
        q.x=(f16)(-bv.x); q.y=(f16)(-bv.y); q.z=(f16)(-bv.z); q.w=(f16)(-bv.w); // -nx
      }
      *(f16x4*)(fr + IN_F + c)     = p;
      *(f16x4*)(fr + 2 * IN_F + c) = q;
    }
  }
  __syncthreads();

  int cur = 0;
  for (int pass = 0; pass < NPASS; pass++) {
    const uint2* ti = tI + pass * 2048;
    const float4* tc = tC + (size_t)pass * 4096;
    const float4* bc = buf + cur * 4096;
    float4* bn = buf + (cur ^ 1) * 4096;
#pragma unroll
    for (int i = 0; i < 2; i++) {
      int g = i * 1024 + t;             // output pair index 0..2047
      uint2 pk = ti[g];
      float4 cA = tc[2 * g], cB = tc[2 * g + 1];
      float4 x0 = bc[SW(pk.x & 0xffff)], x1 = bc[SW(pk.x >> 16)];
      float4 x2 = bc[SW(pk.y & 0xffff)], x3 = bc[SW(pk.y >> 16)];
      bn[SW(2 * g)]     = f4comb(cA, x0, x1, x2, x3);
      bn[SW(2 * g + 1)] = f4comb(cB, x0, x1, x2, x3);
    }
    cur ^= 1;
    __syncthreads();
  }
  // result in plane 0 (6 passes); plane 1 dead -> reduction scratch.
  float lmin = 3.4e38f, lmax = -3.4e38f;
  {
    int c = t * 4;
    float4 q0 = buf[SW(c + 0)];
    float4 q1 = buf[SW(c + 1)];
    float4 q2 = buf[SW(c + 2)];
    float4 q3 = buf[SW(c + 3)];
    ((float4*)(tout + (m0 + 0) * IN_F))[t] = make_float4(q0.x, q1.x, q2.x, q3.x);
    ((float4*)(tout + (m0 + 1) * IN_F))[t] = make_float4(q0.y, q1.y, q2.y, q3.y);
    ((float4*)(tout + (m0 + 2) * IN_F))[t] = make_float4(q0.z, q1.z, q2.z, q3.z);
    ((float4*)(tout + (m0 + 3) * IN_F))[t] = make_float4(q0.w, q1.w, q2.w, q3.w);
    float mn0 = fminf(fminf(q0.x, q0.y), fminf(q0.z, q0.w));
    float mn1 = fminf(fminf(q1.x, q1.y), fminf(q1.z, q1.w));
    float mn2 = fminf(fminf(q2.x, q2.y), fminf(q2.z, q2.w));
    float mn3 = fminf(fminf(q3.x, q3.y), fminf(q3.z, q3.w));
    float mx0 = fmaxf(fmaxf(q0.x, q0.y), fmaxf(q0.z, q0.w));
    float mx1 = fmaxf(fmaxf(q1.x, q1.y), fmaxf(q1.z, q1.w));
    float mx2 = fmaxf(fmaxf(q2.x, q2.y), fmaxf(q2.z, q2.w));
    float mx3 = fmaxf(fmaxf(q3.x, q3.y), fmaxf(q3.z, q3.w));
    lmin = fminf(fminf(mn0, mn1), fminf(mn2, mn3));
    lmax = fmaxf(fmaxf(mx0, mx1), fmaxf(mx2, mx3));
  }
#pragma unroll
  for (int off = 32; off > 0; off >>= 1) {
    lmin = fminf(lmin, __shfl_down(lmin, off));
    lmax = fmaxf(lmax, __shfl_down(lmax, off));
  }
  float* red = (float*)(buf + 4096);
  int wid = t >> 6;
  if ((t & 63) == 0) { red[wid * 2] = lmin; red[wid * 2 + 1] = lmax; }
  __syncthreads();
  if (t == 0) {
    float bmin = red[0], bmax = red[1];
#pragma unroll
    for (int i = 1; i < 16; i++) {
      bmin = fminf(bmin, red[i * 2]);
      bmax = fmaxf(bmax, red[i * 2 + 1]);
    }
    atomicMin(&mm[mmidx], enc_f(bmin));
    atomicMax(&mm[mmidx + 1], enc_f(bmax));
  }
}

__global__ void finalize_kernel(unsigned* mm) {
  float* sc = (float*)(mm + 4);
  float xlo = dec_f(mm[0]), xhi = dec_f(mm[1]);
  float wlo = dec_f(mm[2]), whi = dec_f(mm[3]);
  float sx = (xhi - xlo) / 255.0f;
  float zx = rintf(-128.0f - xlo / sx);
  float sw = (whi - wlo) / 255.0f;
  float zw = rintf(-128.0f - wlo / sw);
  sc[0] = sx; sc[1] = zx; sc[2] = sw; sc[3] = zw;
}

// quantize->dequantize rows into f16 at stride KTOT; 4 rows/block.
__global__ __launch_bounds__(256) void quant_kernel(
    const float* __restrict__ xt, const float* __restrict__ wt,
    f16* __restrict__ Aall, f16* __restrict__ Ball,
    const unsigned* __restrict__ mm) {
  const float* sc = (const float*)(mm + 4);
  const bool isW = blockIdx.x >= (MROWS / 4);
  size_t m0 = (size_t)(isW ? blockIdx.x - MROWS / 4 : blockIdx.x) * 4;
  float s = isW ? sc[2] : sc[0], zp = isW ? sc[3] : sc[1];
  int t = threadIdx.x;
#pragma unroll
  for (int r = 0; r < 4; r++) {
    const float4* srow = (const float4*)((isW ? wt : xt) + (m0 + r) * IN_F);
    f16* drow = (isW ? Ball : Aall) + (m0 + r) * KTOT;
#pragma unroll
    for (int j = 0; j < 4; j++) {
      int i4 = j * 256 + t;
      float4 v = srow[i4];
      float q0 = (fminf(fmaxf(rintf(v.x / s + zp), -128.f), 127.f) - zp) * s;
      float q1 = (fminf(fmaxf(rintf(v.y / s + zp), -128.f), 127.f) - zp) * s;
      float q2 = (fminf(fmaxf(rintf(v.z / s + zp), -128.f), 127.f) - zp) * s;
      float q3 = (fminf(fmaxf(rintf(v.w / s + zp), -128.f), 127.f) - zp) * s;
      f16x4 o; o.x = (f16)q0; o.y = (f16)q1; o.z = (f16)q2; o.w = (f16)q3;
      *(f16x4*)(drow + i4 * 4) = o;
    }
  }
}

// out[m, n] = bias[n]  (pre-init for atomic GEMM epilogue)
__global__ __launch_bounds__(256) void bias_init_kernel(
    const float* __restrict__ bias, float* __restrict__ out) {
  const float4* b4 = (const float4*)bias;
  float4* o4 = (float4*)out;
  int idx = blockIdx.x * 256 + threadIdx.x;
  const int total = MROWS * OUT_F / 4;
  for (int i = idx; i < total; i += gridDim.x * 256)
    o4[i] = b4[i & (OUT_F / 4 - 1)];
}

// ---------------------------------------------------------------------------
// GEMM: out += A_all[8192,12288] @ B_all[1024,12288]^T   (split-K = 2)
// 256x256 tile, BK=64, 8 waves (2Mx4N), 8-phase counted-vmcnt pipeline,
// full 3-bit chunk-XOR LDS swizzle (R6: bank conflicts == 0), bijective XCD
// swizzle. R7: all 24 ds_reads issued in j0 ordered by consumer (counted
// lgkmcnt overlaps LDS drain with j0/j1 MFMA); j3 vmcnt after its MFMA.
//
// Pipeline ledger (tile t, phases j0..j3; half order h0=Alo h1=Ahi h2=Blo h3=Bhi):
//   j0: read all frags (buf t%2), issue (t+1).h2   [t+1 -> buf (t+1)%2]
//   j1: issue (t+1).h3
//   j2: issue (t+2).h0   [t+2 -> buf t%2: safe, all reads of buf t%2
//   j3: issue (t+2).h1    were issued in j0, 3+ barriers earlier]
//       MFMA; vmcnt(4) -> all of tile t+1 landed; BAR
// ---------------------------------------------------------------------------
__device__ __forceinline__ void gl2lds16(const void* g, void* l) {
  __builtin_amdgcn_global_load_lds(
      (__attribute__((address_space(1))) void*)g,
      (__attribute__((address_space(3))) void*)l, 16, 0, 0);
}

#define GBAR() asm volatile("s_barrier" ::: "memory")
#define MFMA16(d, va, vb) d = __builtin_amdgcn_mfma_f32_16x16x32_f16(va, vb, d, 0, 0, 0)

#define STAGE(t, hh) do {                                                   \
    const int c_ = (t) & 1;                                                 \
    if ((hh) < 2) {                                                         \
      const f16* g_ = gA + (size_t)((hh) * 128) * KTOT + (size_t)(t) * 64;  \
      f16* l_ = As + c_ * 16384 + (hh) * 8192 + sbase;                      \
      gl2lds16(g_, l_);                                                     \
      gl2lds16(g_ + (size_t)64 * KTOT, l_ + 4096);                          \
    } else {                                                                \
      const f16* g_ = gB + (size_t)(((hh) - 2) * 128) * KTOT + (size_t)(t) * 64; \
      f16* l_ = Bs + c_ * 16384 + ((hh) - 2) * 8192 + sbase;                \
      gl2lds16(g_, l_);                                                     \
      gl2lds16(g_ + (size_t)64 * KTOT, l_ + 4096);                          \
    }                                                                       \
  } while (0)

__global__ __launch_bounds__(512, 2) void gemm_kernel(
    const f16* __restrict__ A, const f16* __restrict__ B,
    float* __restrict__ out) {
  extern __shared__ f16 sm[];        // 128 KB: As[2][16384] | Bs[2][16384]
  f16* As = sm;
  f16* Bs = sm + 32768;

  const int tid = threadIdx.x;
  const int wave = tid >> 6, lane = tid & 63;
  const int fr = lane & 15, quad = lane >> 4;
  const int wm = wave >> 2, wn = wave & 3;

  // bijective XCD swizzle: 256 blocks, 32 consecutive wg per XCD = one
  // (ks,bn) stripe with bm 0..31 (B panel stays in that XCD's L2).
  const int orig = blockIdx.x;
  const int wg = (orig & 7) * 32 + (orig >> 3);
  const int ks = wg >> 7;
  const int rem = wg & 127;
  const int bn = rem >> 5, bm = rem & 31;
  const size_t k0 = (size_t)ks * KHALF;

  // ---- staging coords: 512 thr x 16B = 8KB/instr; half-tile (128x64 f16) = 2 instr.
  // Pre-swizzled global chunk: (lane&7) ^ (lane>>3)  (row = lane>>3).
  const int srow = (wave << 3) + (lane >> 3);                   // 0..63
  const int scol = (((lane & 7) ^ (lane >> 3)) << 3);           // swizzled 16B chunk
  const f16* gA = A + ((size_t)bm * 256 + srow) * KTOT + k0 + scol;
  const f16* gB = B + ((size_t)bn * 256 + srow) * KTOT + k0 + scol;
  const int sbase = wave << 9;                                  // wave*8 rows * 64

  // ---- ds_read frag addressing: row = (16-row-block)+fr; chunk q and q+4,
  // swizzled by row&7 == fr&7.  co1 = co0 ^ 32 f16 (chunk bit2).
  const int co0 = ((quad ^ (fr & 7)) << 3);
  const int co1 = co0 ^ 32;
  const f16* rA0 = As + wm * 8192 + fr * 64 + co0;
  const f16* rA1 = As + wm * 8192 + fr * 64 + co1;
  const f16* rB0 = Bs + (wn >> 1) * 8192 + (wn & 1) * 4096 + fr * 64 + co0;
  const f16* rB1 = Bs + (wn >> 1) * 8192 + (wn & 1) * 4096 + fr * 64 + co1;

  f16x8 a0[4][2], a1[4][2], bF[4][2];
  f32x4 acc[8][4] = {};

  // ---- prologue: tile0 fully + tile1 h0,h1; wait tile0 (4 newest may fly).
  STAGE(0, 0); STAGE(0, 1); STAGE(0, 2); STAGE(0, 3);
  STAGE(1, 0); STAGE(1, 1);
  asm volatile("s_waitcnt vmcnt(4)" ::: "memory");
  GBAR();

  for (int t = 0; t < NTIL; ++t) {
    const int c = t & 1;
    const f16* pa0 = rA0 + c * 16384;
    const f16* pa1 = rA1 + c * 16384;
    const f16* pb0 = rB0 + c * 16384;
    const f16* pb1 = rB1 + c * 16384;

    // ---------------- phase j0: all reads (consumer order), Q(A0-3,B0-1) ----
#pragma unroll
    for (int i = 0; i < 4; i++) {
      a0[i][0] = *(const f16x8*)(pa0 + i * 1024);
      a0[i][1] = *(const f16x8*)(pa1 + i * 1024);
    }
#pragma unroll
    for (int j = 0; j < 2; j++) {
      bF[j][0] = *(const f16x8*)(pb0 + j * 1024);
      bF[j][1] = *(const f16x8*)(pb1 + j * 1024);
    }
#pragma unroll
    for (int j = 0; j < 2; j++) {
      bF[2 + j][0] = *(const f16x8*)(pb0 + (2 + j) * 1024);
      bF[2 + j][1] = *(const f16x8*)(pb1 + (2 + j) * 1024);
    }
#pragma unroll
    for (int i = 0; i < 4; i++) {
      a1[i][0] = *(const f16x8*)(pa0 + (4 + i) * 1024);
      a1[i][1] = *(const f16x8*)(pa1 + (4 + i) * 1024);
    }
    if (t + 1 < NTIL) STAGE(t + 1, 2);
    GBAR();
    __builtin_amdgcn_s_setprio(1);
#pragma unroll
    for (int i = 0; i < 4; i++)
#pragma unroll
      for (int j = 0; j < 2; j++) {
        MFMA16(acc[i][j], a0[i][0], bF[j][0]);
        MFMA16(acc[i][j], a0[i][1], bF[j][1]);
      }
    __builtin_amdgcn_s_setprio(0);
    GBAR();

    // ---------------- phase j1: Q(A0-3,B2-3) ----------------
    if (t + 1 < NTIL) STAGE(t + 1, 3);
    GBAR();
    __builtin_amdgcn_s_setprio(1);
#pragma unroll
    for (int i = 0; i < 4; i++)
#pragma unroll
      for (int j = 0; j < 2; j++) {
        MFMA16(acc[i][2 + j], a0[i][0], bF[2 + j][0]);
        MFMA16(acc[i][2 + j], a0[i][1], bF[2 + j][1]);
      }
    __builtin_amdgcn_s_setprio(0);
    GBAR();

    // ---------------- phase j2: Q(A4-7,B0-1) ----------------
    if (t + 2 < NTIL) STAGE(t + 2, 0);
    GBAR();
    __builtin_amdgcn_s_setprio(1);
#pragma unroll
    for (int i = 0; i < 4; i++)
#pragma unroll
      for (int j = 0; j < 2; j++) {
        MFMA16(acc[4 + i][j], a1[i][0], bF[j][0]);
        MFMA16(acc[4 + i][j], a1[i][1], bF[j][1]);
      }
    __builtin_amdgcn_s_setprio(0);
    GBAR();

    // ---------------- phase j3: Q(A4-7,B2-3); vmcnt after MFMA ----------------
    if (t + 2 < NTIL) STAGE(t + 2, 1);
    GBAR();
    __builtin_amdgcn_s_setprio(1);
#pragma unroll
    for (int i = 0; i < 4; i++)
#pragma unroll
      for (int j = 0; j < 2; j++) {
        MFMA16(acc[4 + i][2 + j], a1[i][0], bF[2 + j][0]);
        MFMA16(acc[4 + i][2 + j], a1[i][1], bF[2 + j][1]);
      }
    __builtin_amdgcn_s_setprio(0);
    if (t + 2 < NTIL) {
      asm volatile("s_waitcnt vmcnt(4)" ::: "memory");   // tile t+1 landed
    } else if (t + 1 < NTIL) {
      asm volatile("s_waitcnt vmcnt(0)" ::: "memory");   // last prefetch drained
    }
    GBAR();
  }

  // ---- epilogue: D row = quad*4+reg, col = lane&15 (16x16x32 layout)
  const size_t orow = (size_t)bm * 256 + wm * 128 + quad * 4;
  const int ocol = bn * 256 + wn * 64 + fr;
#pragma unroll
  for (int mi = 0; mi < 8; mi++)
#pragma unroll
    for (int ni = 0; ni < 4; ni++)
#pragma unroll
      for (int e = 0; e < 4; e++)
        unsafeAtomicAdd(&out[(orow + mi * 16 + e) * OUT_F + (ocol + ni * 16)],
                        acc[mi][ni][e]);
}

// ---------------------------------------------------------------------------
extern "C" void kernel_launch(void* const* d_in, const int* in_sizes, int n_in,
                              void* d_out, int out_size, void* d_ws, size_t ws_size,
                              hipStream_t stream) {
  const float* x     = (const float*)d_in[0];
  const float* w     = (const float*)d_in[1];
  const float* bias  = (const float*)d_in[2];
  const float* wn    = (const float*)d_in[3];
  const float* nx    = (const float*)d_in[4];
  const int*   perms = (const int*)d_in[5];
  const float* mats  = (const float*)d_in[6];
  float* out = (float*)d_out;

  char* ws = (char*)d_ws;                       // needs ~379 MB
  float* xt   = (float*)(ws + OFF_XT);
  float* wt   = (float*)(ws + OFF_WT);
  f16*   Aall = (f16*)(ws + OFF_A);
  f16*   Ball = (f16*)(ws + OFF_B);
  unsigned* mm = (unsigned*)(ws + OFF_MM);
  uint2*  tIx = (uint2*)(ws + OFF_TIX);
  float4* tCx = (float4*)(ws + OFF_TCX);
  uint2*  tIw = (uint2*)(ws + OFF_TIW);
  float4* tCw = (float4*)(ws + OFF_TCW);

  static int attr_set = 0;
  if (!attr_set) {
    (void)hipFuncSetAttribute(reinterpret_cast<const void*>(gemm_kernel),
                              hipFuncAttributeMaxDynamicSharedMemorySize, 131072);
    (void)hipFuncSetAttribute(reinterpret_cast<const void*>(transform_kernel),
                              hipFuncAttributeMaxDynamicSharedMemorySize, 131072);
    attr_set = 1;
  }

  build_tables_kernel<<<NPASS, 256, 0, stream>>>(perms, mats, tIx, tCx, tIw, tCw, mm);
  transform_kernel<<<MROWS / 4 + OUT_F / 4, 1024, 131072, stream>>>(
      x, nx, w, wn, tIx, tCx, tIw, tCw, xt, wt, Aall, Ball, mm);
  finalize_kernel<<<1, 1, 0, stream>>>(mm);
  quant_kernel<<<(MROWS + OUT_F) / 4, 256, 0, stream>>>(xt, wt, Aall, Ball, mm);
  bias_init_kernel<<<1024, 256, 0, stream>>>(bias, out);
  gemm_kernel<<<2 * (MROWS / 256) * (OUT_F / 256), 512, 131072, stream>>>(Aall, Ball, out);
}

// Round 5
// 661.513 us; speedup vs baseline: 1.0341x; 1.0341x over previous
//
#include <hip/hip_runtime.h>

// ---------------------------------------------------------------------------
// QuantizedPermutationNoiseLinear  (B=4, S=2048, IN=4096, OUT=1024, ROUNDS=12)
//
// res = QDQ(T(x+nx)) @ QDQ(Tw(w+wn)).T + bias - x@wn.T - nx@(w+wn).T
//
// R8 changes vs R7:
//  - gemm: 8 barriers/K-tile -> 2. All frag reads in j0 (R7) means only two
//    sync points are structurally needed: lgkmcnt(0)+BAR before the t+2
//    stage overwrites buf c, and vmcnt(4)+BAR at tile end. 32-MFMA clusters.
//    Also closes R7's latent read-vs-gl2lds-land race (explicit lgkm drain).
//  - build_tables: 48 blocks (was 6; grid-too-small latency).
//  - bias_init folded into quant grid (one fewer launch).
//  - transform unchanged (R6->R7 A/B: table traffic + occupancy both null).
// ---------------------------------------------------------------------------

#define IN_F   4096
#define OUT_F  1024
#define MROWS  8192          // B*S
#define KTOT   12288
#define KHALF  6144
#define NPASS  6             // merged rounds (12 -> 6)
#define NTIL   96            // K-tiles per split (6144/64)

typedef _Float16 f16;
typedef _Float16 f16x8 __attribute__((ext_vector_type(8)));
typedef _Float16 f16x4 __attribute__((ext_vector_type(4)));
typedef float    f32x4 __attribute__((ext_vector_type(4)));

// ---- workspace layout (bytes) --- total ~379 MB ---------------------------
#define OFF_XT  (0ull)                                   // 8192*4096*4 = 128 MB
#define OFF_WT  (OFF_XT + (size_t)MROWS * IN_F * 4)      // 1024*4096*4 = 16 MB
#define OFF_A   (OFF_WT + (size_t)OUT_F * IN_F * 4)      // 8192*12288*2 = 192 MB
#define OFF_B   (OFF_A + (size_t)MROWS * KTOT * 2)       // 1024*12288*2 = 24 MB
#define OFF_MM  (OFF_B + (size_t)OUT_F * KTOT * 2)       // 4 u32 + 4 f32
#define OFF_TIX (OFF_MM + 256)                           // 6*2048*8  = 96 KB
#define OFF_TCX (OFF_TIX + (size_t)NPASS * 2048 * 8)     // 6*2048*32 = 384 KB
#define OFF_TIW (OFF_TCX + (size_t)NPASS * 2048 * 32)
#define OFF_TCW (OFF_TIW + (size_t)NPASS * 2048 * 8)

// LDS slot swizzle (transform): spreads stride-4 float4 writes across all
// eight 16B positions per 128B period.
#define SW(s) ((s) ^ (((s) >> 3) & 7))

// ---- sortable-uint encoding for float atomic min/max ----------------------
__device__ __forceinline__ unsigned enc_f(float f) {
  unsigned u = __float_as_uint(f);
  return (u & 0x80000000u) ? ~u : (u | 0x80000000u);
}
__device__ __forceinline__ float dec_f(unsigned u) {
  unsigned b = (u & 0x80000000u) ? (u & 0x7fffffffu) : ~u;
  return __uint_as_float(b);
}

__device__ __forceinline__ float4 f4comb(float4 c, float4 x0, float4 x1,
                                         float4 x2, float4 x3) {
  return make_float4(c.x * x0.x + c.y * x1.x + c.z * x2.x + c.w * x3.x,
                     c.x * x0.y + c.y * x1.y + c.z * x2.y + c.w * x3.y,
                     c.x * x0.z + c.y * x1.z + c.z * x2.z + c.w * x3.z,
                     c.x * x0.w + c.y * x1.w + c.z * x2.w + c.w * x3.w);
}

// ---------------------------------------------------------------------------
// Build merged-round tables. 48 blocks: p = blk/8, g = (blk%8)*256 + tid.
// ---------------------------------------------------------------------------
__global__ __launch_bounds__(256) void build_tables_kernel(
    const int* __restrict__ perms, const float* __restrict__ mats,
    uint2* __restrict__ tIx, float4* __restrict__ tCx,
    uint2* __restrict__ tIw, float4* __restrict__ tCw,
    unsigned* __restrict__ mm) {
  if (blockIdx.x == 0 && threadIdx.x == 0) {
    mm[0] = 0xFFFFFFFFu; mm[1] = 0u; mm[2] = 0xFFFFFFFFu; mm[3] = 0u;
  }
  int p = blockIdx.x >> 3;                       // 0..5
  int g = ((blockIdx.x & 7) << 8) + threadIdx.x; // 0..2047
  int r0 = 2 * p, r1 = 2 * p + 1;
  {
    int q0 = perms[r1 * IN_F + 2 * g], q1 = perms[r1 * IN_F + 2 * g + 1];
    int a0 = q0 >> 1, e0 = q0 & 1, a1 = q1 >> 1, e1 = q1 & 1;
    unsigned i0 = perms[r0 * IN_F + 2 * a0], i1 = perms[r0 * IN_F + 2 * a0 + 1];
    unsigned i2 = perms[r0 * IN_F + 2 * a1], i3 = perms[r0 * IN_F + 2 * a1 + 1];
    uint2 idx = make_uint2(i0 | (i1 << 16), i2 | (i3 << 16));
    const float* Ma = mats + ((size_t)r0 * 2048 + a0) * 4;  // [a,b,c,d]
    const float* Mb = mats + ((size_t)r0 * 2048 + a1) * 4;
    const float* M1 = mats + ((size_t)r1 * 2048 + g) * 4;
    int o = p * 2048 + g;
    { // forward
      float c00 = Ma[e0 * 2], c01 = Ma[e0 * 2 + 1];
      float c10 = Mb[e1 * 2], c11 = Mb[e1 * 2 + 1];
      float m00 = M1[0], m01 = M1[1], m10 = M1[2], m11 = M1[3];
      tIx[o] = idx;
      tCx[2 * o]     = make_float4(m00 * c00, m00 * c01, m01 * c10, m01 * c11);
      tCx[2 * o + 1] = make_float4(m10 * c00, m10 * c01, m11 * c10, m11 * c11);
    }
    { // inverse-transpose (weight): N = [[d,-c],[-b,a]]/det
      float rda = 1.0f / (Ma[0] * Ma[3] - Ma[1] * Ma[2]);
      float rdb = 1.0f / (Mb[0] * Mb[3] - Mb[1] * Mb[2]);
      float rd1 = 1.0f / (M1[0] * M1[3] - M1[1] * M1[2]);
      float c00 = (e0 == 0 ? Ma[3] : -Ma[1]) * rda;
      float c01 = (e0 == 0 ? -Ma[2] : Ma[0]) * rda;
      float c10 = (e1 == 0 ? Mb[3] : -Mb[1]) * rdb;
      float c11 = (e1 == 0 ? -Mb[2] : Mb[0]) * rdb;
      float m00 = M1[3] * rd1, m01 = -M1[2] * rd1;
      float m10 = -M1[1] * rd1, m11 = M1[0] * rd1;
      tIw[o] = idx;
      tCw[2 * o]     = make_float4(m00 * c00, m00 * c01, m01 * c10, m01 * c11);
      tCw[2 * o + 1] = make_float4(m10 * c00, m10 * c01, m11 * c10, m11 * c11);
    }
  }
}

// ---------------------------------------------------------------------------
// Transform: 1024 threads, 4 rows/block (float4-packed), 6 merged LDS passes.
// 128 KB dynamic LDS = 2 planes x 4096 float4, XOR slot swizzle.
// ---------------------------------------------------------------------------
__global__ __launch_bounds__(1024) void transform_kernel(
    const float* __restrict__ x, const float* __restrict__ nx,
    const float* __restrict__ w, const float* __restrict__ wn,
    const uint2* __restrict__ tIx, const float4* __restrict__ tCx,
    const uint2* __restrict__ tIw, const float4* __restrict__ tCw,
    float* __restrict__ xt, float* __restrict__ wt,
    f16* __restrict__ Aall, f16* __restrict__ Ball,
    unsigned* __restrict__ mm) {
  extern __shared__ float4 buf[];   // [2][4096]
  const int t = threadIdx.x;
  const bool isW = blockIdx.x >= (MROWS / 4);
  const float *in0, *in1; const uint2* tI; const float4* tC;
  float* tout; f16* fout; int mmidx; size_t m0;
  if (!isW) {
    m0 = (size_t)blockIdx.x * 4;
    in0 = x; in1 = nx; tI = tIx; tC = tCx; tout = xt; fout = Aall; mmidx = 0;
  } else {
    m0 = (size_t)(blockIdx.x - MROWS / 4) * 4;
    in0 = w; in1 = wn; tI = tIw; tC = tCw; tout = wt; fout = Ball; mmidx = 2;
  }

  { // load 4 rows, pack columns into float4 slots, emit f16 side-outputs
    float4 a0 = ((const float4*)(in0 + (m0 + 0) * IN_F))[t];
    float4 a1 = ((const float4*)(in0 + (m0 + 1) * IN_F))[t];
    float4 a2 = ((const float4*)(in0 + (m0 + 2) * IN_F))[t];
    float4 a3 = ((const float4*)(in0 + (m0 + 3) * IN_F))[t];
    float4 b0 = ((const float4*)(in1 + (m0 + 0) * IN_F))[t];
    float4 b1 = ((const float4*)(in1 + (m0 + 1) * IN_F))[t];
    float4 b2 = ((const float4*)(in1 + (m0 + 2) * IN_F))[t];
    float4 b3 = ((const float4*)(in1 + (m0 + 3) * IN_F))[t];
    float4 s0 = make_float4(a0.x + b0.x, a0.y + b0.y, a0.z + b0.z, a0.w + b0.w);
    float4 s1 = make_float4(a1.x + b1.x, a1.y + b1.y, a1.z + b1.z, a1.w + b1.w);
    float4 s2 = make_float4(a2.x + b2.x, a2.y + b2.y, a2.z + b2.z, a2.w + b2.w);
    float4 s3 = make_float4(a3.x + b3.x, a3.y + b3.y, a3.z + b3.z, a3.w + b3.w);
    int c = t * 4;
    buf[SW(c + 0)] = make_float4(s0.x, s1.x, s2.x, s3.x);
    buf[SW(c + 1)] = make_float4(s0.y, s1.y, s2.y, s3.y);
    buf[SW(c + 2)] = make_float4(s0.z, s1.z, s2.z, s3.z);
    buf[SW(c + 3)] = make_float4(s0.w, s1.w, s2.w, s3.w);
#pragma unroll
    for (int r = 0; r < 4; r++) {
      float4 av = r == 0 ? a0 : r == 1 ? a1 : r == 2 ? a2 : a3;
      float4 bv = r == 0 ? b0 : r == 1 ? b1 : r == 2 ? b2 : b3;
      float4 sv = r == 0 ? s0 : r == 1 ? s1 : r == 2 ? s2 : s3;
      f16* fr = fout + (m0 + r) * KTOT;
      f16x4 p, q;
      if (isW) {
        p.x=(f16)bv.x; p.y=(f16)bv.y; p.z=(f16)bv.z; p.w=(f16)bv.w;   // wn
        q.x=(f16)sv.x; q.y=(f16)sv.y; q.z=(f16)sv.z; q.w=(f16)sv.w;   // w+wn
      } else {
        p.x=(f16)(-av.x); p.y=(f16)(-av.y); p.z=(f16)(-av.z); p.w=(f16)(-av.w); // -x
        q.x=(f16)(-bv.x); q.y=(f16)(-bv.y); q.z=(f16)(-bv.z); q.w=(f16)(-bv.w); // -nx
      }
      *(f16x4*)(fr + IN_F + c)     = p;
      *(f16x4*)(fr + 2 * IN_F + c) = q;
    }
  }
  __syncthreads();

  int cur = 0;
  for (int pass = 0; pass < NPASS; pass++) {
    const uint2* ti = tI + pass * 2048;
    const float4* tc = tC + (size_t)pass * 4096;
    const float4* bc = buf + cur * 4096;
    float4* bn = buf + (cur ^ 1) * 4096;
#pragma unroll
    for (int i = 0; i < 2; i++) {
      int g = i * 1024 + t;             // output pair index 0..2047
      uint2 pk = ti[g];
      float4 cA = tc[2 * g], cB = tc[2 * g + 1];
      float4 x0 = bc[SW(pk.x & 0xffff)], x1 = bc[SW(pk.x >> 16)];
      float4 x2 = bc[SW(pk.y & 0xffff)], x3 = bc[SW(pk.y >> 16)];
      bn[SW(2 * g)]     = f4comb(cA, x0, x1, x2, x3);
      bn[SW(2 * g + 1)] = f4comb(cB, x0, x1, x2, x3);
    }
    cur ^= 1;
    __syncthreads();
  }
  // result in plane 0 (6 passes); plane 1 dead -> reduction scratch.
  float lmin = 3.4e38f, lmax = -3.4e38f;
  {
    int c = t * 4;
    float4 q0 = buf[SW(c + 0)];
    float4 q1 = buf[SW(c + 1)];
    float4 q2 = buf[SW(c + 2)];
    float4 q3 = buf[SW(c + 3)];
    ((float4*)(tout + (m0 + 0) * IN_F))[t] = make_float4(q0.x, q1.x, q2.x, q3.x);
    ((float4*)(tout + (m0 + 1) * IN_F))[t] = make_float4(q0.y, q1.y, q2.y, q3.y);
    ((float4*)(tout + (m0 + 2) * IN_F))[t] = make_float4(q0.z, q1.z, q2.z, q3.z);
    ((float4*)(tout + (m0 + 3) * IN_F))[t] = make_float4(q0.w, q1.w, q2.w, q3.w);
    float mn0 = fminf(fminf(q0.x, q0.y), fminf(q0.z, q0.w));
    float mn1 = fminf(fminf(q1.x, q1.y), fminf(q1.z, q1.w));
    float mn2 = fminf(fminf(q2.x, q2.y), fminf(q2.z, q2.w));
    float mn3 = fminf(fminf(q3.x, q3.y), fminf(q3.z, q3.w));
    float mx0 = fmaxf(fmaxf(q0.x, q0.y), fmaxf(q0.z, q0.w));
    float mx1 = fmaxf(fmaxf(q1.x, q1.y), fmaxf(q1.z, q1.w));
    float mx2 = fmaxf(fmaxf(q2.x, q2.y), fmaxf(q2.z, q2.w));
    float mx3 = fmaxf(fmaxf(q3.x, q3.y), fmaxf(q3.z, q3.w));
    lmin = fminf(fminf(mn0, mn1), fminf(mn2, mn3));
    lmax = fmaxf(fmaxf(mx0, mx1), fmaxf(mx2, mx3));
  }
#pragma unroll
  for (int off = 32; off > 0; off >>= 1) {
    lmin = fminf(lmin, __shfl_down(lmin, off));
    lmax = fmaxf(lmax, __shfl_down(lmax, off));
  }
  float* red = (float*)(buf + 4096);
  int wid = t >> 6;
  if ((t & 63) == 0) { red[wid * 2] = lmin; red[wid * 2 + 1] = lmax; }
  __syncthreads();
  if (t == 0) {
    float bmin = red[0], bmax = red[1];
#pragma unroll
    for (int i = 1; i < 16; i++) {
      bmin = fminf(bmin, red[i * 2]);
      bmax = fmaxf(bmax, red[i * 2 + 1]);
    }
    atomicMin(&mm[mmidx], enc_f(bmin));
    atomicMax(&mm[mmidx + 1], enc_f(bmax));
  }
}

__global__ void finalize_kernel(unsigned* mm) {
  float* sc = (float*)(mm + 4);
  float xlo = dec_f(mm[0]), xhi = dec_f(mm[1]);
  float wlo = dec_f(mm[2]), whi = dec_f(mm[3]);
  float sx = (xhi - xlo) / 255.0f;
  float zx = rintf(-128.0f - xlo / sx);
  float sw = (whi - wlo) / 255.0f;
  float zw = rintf(-128.0f - wlo / sw);
  sc[0] = sx; sc[1] = zx; sc[2] = sw; sc[3] = zw;
}

// quantize->dequantize rows into f16 at stride KTOT; 4 rows/block.
// Tail blocks (>= NQB) do the bias pre-init for the atomic GEMM epilogue.
#define NQB ((MROWS + OUT_F) / 4)
__global__ __launch_bounds__(256) void quant_kernel(
    const float* __restrict__ xt, const float* __restrict__ wt,
    f16* __restrict__ Aall, f16* __restrict__ Ball,
    const unsigned* __restrict__ mm,
    const float* __restrict__ bias, float* __restrict__ out) {
  if (blockIdx.x >= NQB) {                      // bias init: 512 blocks
    const float4* b4 = (const float4*)bias;
    float4* o4 = (float4*)out;
    int idx = (blockIdx.x - NQB) * 256 + threadIdx.x;
    const int total = MROWS * OUT_F / 4;
    for (int i = idx; i < total; i += 512 * 256)
      o4[i] = b4[i & (OUT_F / 4 - 1)];
    return;
  }
  const float* sc = (const float*)(mm + 4);
  const bool isW = blockIdx.x >= (MROWS / 4);
  size_t m0 = (size_t)(isW ? blockIdx.x - MROWS / 4 : blockIdx.x) * 4;
  float s = isW ? sc[2] : sc[0], zp = isW ? sc[3] : sc[1];
  int t = threadIdx.x;
#pragma unroll
  for (int r = 0; r < 4; r++) {
    const float4* srow = (const float4*)((isW ? wt : xt) + (m0 + r) * IN_F);
    f16* drow = (isW ? Ball : Aall) + (m0 + r) * KTOT;
#pragma unroll
    for (int j = 0; j < 4; j++) {
      int i4 = j * 256 + t;
      float4 v = srow[i4];
      float q0 = (fminf(fmaxf(rintf(v.x / s + zp), -128.f), 127.f) - zp) * s;
      float q1 = (fminf(fmaxf(rintf(v.y / s + zp), -128.f), 127.f) - zp) * s;
      float q2 = (fminf(fmaxf(rintf(v.z / s + zp), -128.f), 127.f) - zp) * s;
      float q3 = (fminf(fmaxf(rintf(v.w / s + zp), -128.f), 127.f) - zp) * s;
      f16x4 o; o.x = (f16)q0; o.y = (f16)q1; o.z = (f16)q2; o.w = (f16)q3;
      *(f16x4*)(drow + i4 * 4) = o;
    }
  }
}

// ---------------------------------------------------------------------------
// GEMM: out += A_all[8192,12288] @ B_all[1024,12288]^T   (split-K = 2)
// 256x256 tile, BK=64, 8 waves (2Mx4N), 2 barriers/K-tile, counted vmcnt,
// full 3-bit chunk-XOR LDS swizzle (R6: conflicts == 0), bijective XCD swz.
//
// K-tile t (buf c = t&1):
//   [ds_read all 24 frags of buf c]  [STAGE t+1.h2,h3]
//   MFMA Q0(a0 x b01), Q1(a0 x b23)
//   s_waitcnt lgkmcnt(0)   // this wave's reads of buf c have EXECUTED
//   BAR1                   // => all waves' reads done; buf c may be rewritten
//   [STAGE t+2.h0,h1 -> buf c]
//   MFMA Q2(a1 x b01), Q3(a1 x b23)
//   s_waitcnt vmcnt(4)     // drains t+1 fully (t+2.h0h1 remain in flight)
//   BAR2                   // tile t+1 visible to all
// In-flight ledger: steady state 12 after stages, 4 after vmcnt. Prologue:
// t0.h0-3 + t1.h0,h1 then vmcnt(4) (t0 landed). Tail: vmcnt(0) at t=NTIL-2.
// ---------------------------------------------------------------------------
__device__ __forceinline__ void gl2lds16(const void* g, void* l) {
  __builtin_amdgcn_global_load_lds(
      (__attribute__((address_space(1))) void*)g,
      (__attribute__((address_space(3))) void*)l, 16, 0, 0);
}

#define GBAR() asm volatile("s_barrier" ::: "memory")
#define MFMA16(d, va, vb) d = __builtin_amdgcn_mfma_f32_16x16x32_f16(va, vb, d, 0, 0, 0)

#define STAGE(t, hh) do {                                                   \
    const int c_ = (t) & 1;                                                 \
    if ((hh) < 2) {                                                         \
      const f16* g_ = gA + (size_t)((hh) * 128) * KTOT + (size_t)(t) * 64;  \
      f16* l_ = As + c_ * 16384 + (hh) * 8192 + sbase;                      \
      gl2lds16(g_, l_);                                                     \
      gl2lds16(g_ + (size_t)64 * KTOT, l_ + 4096);                          \
    } else {                                                                \
      const f16* g_ = gB + (size_t)(((hh) - 2) * 128) * KTOT + (size_t)(t) * 64; \
      f16* l_ = Bs + c_ * 16384 + ((hh) - 2) * 8192 + sbase;                \
      gl2lds16(g_, l_);                                                     \
      gl2lds16(g_ + (size_t)64 * KTOT, l_ + 4096);                          \
    }                                                                       \
  } while (0)

__global__ __launch_bounds__(512, 2) void gemm_kernel(
    const f16* __restrict__ A, const f16* __restrict__ B,
    float* __restrict__ out) {
  extern __shared__ f16 sm[];        // 128 KB: As[2][16384] | Bs[2][16384]
  f16* As = sm;
  f16* Bs = sm + 32768;

  const int tid = threadIdx.x;
  const int wave = tid >> 6, lane = tid & 63;
  const int fr = lane & 15, quad = lane >> 4;
  const int wm = wave >> 2, wn = wave & 3;

  // bijective XCD swizzle: 256 blocks, 32 consecutive wg per XCD = one
  // (ks,bn) stripe with bm 0..31 (B panel stays in that XCD's L2).
  const int orig = blockIdx.x;
  const int wg = (orig & 7) * 32 + (orig >> 3);
  const int ks = wg >> 7;
  const int rem = wg & 127;
  const int bn = rem >> 5, bm = rem & 31;
  const size_t k0 = (size_t)ks * KHALF;

  // ---- staging coords: pre-swizzled global chunk (lane&7)^(lane>>3).
  const int srow = (wave << 3) + (lane >> 3);                   // 0..63
  const int scol = (((lane & 7) ^ (lane >> 3)) << 3);           // swizzled 16B chunk
  const f16* gA = A + ((size_t)bm * 256 + srow) * KTOT + k0 + scol;
  const f16* gB = B + ((size_t)bn * 256 + srow) * KTOT + k0 + scol;
  const int sbase = wave << 9;                                  // wave*8 rows * 64

  // ---- ds_read frag addressing (3-bit chunk XOR; co1 = co0 ^ 32 f16).
  const int co0 = ((quad ^ (fr & 7)) << 3);
  const int co1 = co0 ^ 32;
  const f16* rA0 = As + wm * 8192 + fr * 64 + co0;
  const f16* rA1 = As + wm * 8192 + fr * 64 + co1;
  const f16* rB0 = Bs + (wn >> 1) * 8192 + (wn & 1) * 4096 + fr * 64 + co0;
  const f16* rB1 = Bs + (wn >> 1) * 8192 + (wn & 1) * 4096 + fr * 64 + co1;

  f16x8 a0[4][2], a1[4][2], bF[4][2];
  f32x4 acc[8][4] = {};

  // ---- prologue: tile0 fully + tile1 h0,h1; wait tile0 (4 newest may fly).
  STAGE(0, 0); STAGE(0, 1); STAGE(0, 2); STAGE(0, 3);
  STAGE(1, 0); STAGE(1, 1);
  asm volatile("s_waitcnt vmcnt(4)" ::: "memory");
  GBAR();

  for (int t = 0; t < NTIL; ++t) {
    const int c = t & 1;
    const f16* pa0 = rA0 + c * 16384;
    const f16* pa1 = rA1 + c * 16384;
    const f16* pb0 = rB0 + c * 16384;
    const f16* pb1 = rB1 + c * 16384;

    // ---- reads (consumer order) + early stage of t+1 B halves ----
#pragma unroll
    for (int i = 0; i < 4; i++) {
      a0[i][0] = *(const f16x8*)(pa0 + i * 1024);
      a0[i][1] = *(const f16x8*)(pa1 + i * 1024);
    }
#pragma unroll
    for (int j = 0; j < 4; j++) {
      bF[j][0] = *(const f16x8*)(pb0 + j * 1024);
      bF[j][1] = *(const f16x8*)(pb1 + j * 1024);
    }
#pragma unroll
    for (int i = 0; i < 4; i++) {
      a1[i][0] = *(const f16x8*)(pa0 + (4 + i) * 1024);
      a1[i][1] = *(const f16x8*)(pa1 + (4 + i) * 1024);
    }
    if (t + 1 < NTIL) { STAGE(t + 1, 2); STAGE(t + 1, 3); }

    // ---- MFMA Q0 + Q1 (a0 x all B) ----
    __builtin_amdgcn_s_setprio(1);
#pragma unroll
    for (int i = 0; i < 4; i++)
#pragma unroll
      for (int j = 0; j < 4; j++) {
        MFMA16(acc[i][j], a0[i][0], bF[j][0]);
        MFMA16(acc[i][j], a0[i][1], bF[j][1]);
      }
    __builtin_amdgcn_s_setprio(0);

    // all this wave's ds_reads of buf c have executed -> barrier -> buf c free
    asm volatile("s_waitcnt lgkmcnt(0)" ::: "memory");
    GBAR();
    if (t + 2 < NTIL) { STAGE(t + 2, 0); STAGE(t + 2, 1); }

    // ---- MFMA Q2 + Q3 (a1 x all B) ----
    __builtin_amdgcn_s_setprio(1);
#pragma unroll
    for (int i = 0; i < 4; i++)
#pragma unroll
      for (int j = 0; j < 4; j++) {
        MFMA16(acc[4 + i][j], a1[i][0], bF[j][0]);
        MFMA16(acc[4 + i][j], a1[i][1], bF[j][1]);
      }
    __builtin_amdgcn_s_setprio(0);

    if (t + 2 < NTIL) {
      asm volatile("s_waitcnt vmcnt(4)" ::: "memory");   // tile t+1 landed
    } else if (t + 1 < NTIL) {
      asm volatile("s_waitcnt vmcnt(0)" ::: "memory");   // last prefetch drained
    }
    GBAR();
  }

  // ---- epilogue: D row = quad*4+reg, col = lane&15 (16x16x32 layout)
  const size_t orow = (size_t)bm * 256 + wm * 128 + quad * 4;
  const int ocol = bn * 256 + wn * 64 + fr;
#pragma unroll
  for (int mi = 0; mi < 8; mi++)
#pragma unroll
    for (int ni = 0; ni < 4; ni++)
#pragma unroll
      for (int e = 0; e < 4; e++)
        unsafeAtomicAdd(&out[(orow + mi * 16 + e) * OUT_F + (ocol + ni * 16)],
                        acc[mi][ni][e]);
}

// ---------------------------------------------------------------------------
extern "C" void kernel_launch(void* const* d_in, const int* in_sizes, int n_in,
                              void* d_out, int out_size, void* d_ws, size_t ws_size,
                              hipStream_t stream) {
  const float* x     = (const float*)d_in[0];
  const float* w     = (const float*)d_in[1];
  const float* bias  = (const float*)d_in[2];
  const float* wn    = (const float*)d_in[3];
  const float* nx    = (const float*)d_in[4];
  const int*   perms = (const int*)d_in[5];
  const float* mats  = (const float*)d_in[6];
  float* out = (float*)d_out;

  char* ws = (char*)d_ws;                       // needs ~379 MB
  float* xt   = (float*)(ws + OFF_XT);
  float* wt   = (float*)(ws + OFF_WT);
  f16*   Aall = (f16*)(ws + OFF_A);
  f16*   Ball = (f16*)(ws + OFF_B);
  unsigned* mm = (unsigned*)(ws + OFF_MM);
  uint2*  tIx = (uint2*)(ws + OFF_TIX);
  float4* tCx = (float4*)(ws + OFF_TCX);
  uint2*  tIw = (uint2*)(ws + OFF_TIW);
  float4* tCw = (float4*)(ws + OFF_TCW);

  static int attr_set = 0;
  if (!attr_set) {
    (void)hipFuncSetAttribute(reinterpret_cast<const void*>(gemm_kernel),
                              hipFuncAttributeMaxDynamicSharedMemorySize, 131072);
    (void)hipFuncSetAttribute(reinterpret_cast<const void*>(transform_kernel),
                              hipFuncAttributeMaxDynamicSharedMemorySize, 131072);
    attr_set = 1;
  }

  build_tables_kernel<<<48, 256, 0, stream>>>(perms, mats, tIx, tCx, tIw, tCw, mm);
  transform_kernel<<<MROWS / 4 + OUT_F / 4, 1024, 131072, stream>>>(
      x, nx, w, wn, tIx, tCx, tIw, tCw, xt, wt, Aall, Ball, mm);
  finalize_kernel<<<1, 1, 0, stream>>>(mm);
  quant_kernel<<<NQB + 512, 256, 0, stream>>>(xt, wt, Aall, Ball, mm, bias, out);
  gemm_kernel<<<2 * (MROWS / 256) * (OUT_F / 256), 512, 131072, stream>>>(Aall, Ball, out);
}